// Round 11
// baseline (394.736 us; speedup 1.0000x reference)
//
#include <hip/hip_runtime.h>
#include <hip/hip_bf16.h>
#include <math.h>

#define S_LEN 2048
#define H_DIM 2048
#define NH 16
#define Q_LORA 1536
#define KV_LORA 512
#define D_NOPE 128
#define D_ROPE 64
#define D_V 128
#define D_QK 192

typedef unsigned short ushort_t;
typedef __attribute__((ext_vector_type(8))) short short8;
typedef __attribute__((ext_vector_type(4))) float f32x4;

__device__ __forceinline__ ushort_t f2bf(float f) {
    unsigned int u = __float_as_uint(f);
    u = (u + 0x7FFFu + ((u >> 16) & 1u)) >> 16;
    return (ushort_t)u;
}
__device__ __forceinline__ float bf2f(ushort_t u) {
    return __uint_as_float(((unsigned int)u) << 16);
}

__device__ __forceinline__ void storeC(float* p, float v) { *p = v; }
__device__ __forceinline__ void storeC(ushort_t* p, float v) { *p = f2bf(v); }

__device__ __forceinline__ void gload_lds16(const ushort_t* g, ushort_t* l) {
    __builtin_amdgcn_global_load_lds(
        (const __attribute__((address_space(1))) unsigned int*)(const void*)g,
        (__attribute__((address_space(3))) unsigned int*)(void*)l, 16, 0, 0);
}

// 16-lane DPP-row reductions (pure VALU)
__device__ __forceinline__ float dpp_max16(float x) {
    x = fmaxf(x, __int_as_float(__builtin_amdgcn_update_dpp(0, __float_as_int(x), 0xB1, 0xF, 0xF, true)));
    x = fmaxf(x, __int_as_float(__builtin_amdgcn_update_dpp(0, __float_as_int(x), 0x4E, 0xF, 0xF, true)));
    x = fmaxf(x, __int_as_float(__builtin_amdgcn_update_dpp(0, __float_as_int(x), 0x124, 0xF, 0xF, true)));
    x = fmaxf(x, __int_as_float(__builtin_amdgcn_update_dpp(0, __float_as_int(x), 0x128, 0xF, 0xF, true)));
    return x;
}
__device__ __forceinline__ float dpp_sum16(float x) {
    x += __int_as_float(__builtin_amdgcn_update_dpp(0, __float_as_int(x), 0xB1, 0xF, 0xF, true));
    x += __int_as_float(__builtin_amdgcn_update_dpp(0, __float_as_int(x), 0x4E, 0xF, 0xF, true));
    x += __int_as_float(__builtin_amdgcn_update_dpp(0, __float_as_int(x), 0x124, 0xF, 0xF, true));
    x += __int_as_float(__builtin_amdgcn_update_dpp(0, __float_as_int(x), 0x128, 0xF, 0xF, true));
    return x;
}

// ---------------- fp32 -> bf16 elementwise (n % 4 == 0) ----------------
__global__ __launch_bounds__(256) void conv_f32_bf16(
    const float* __restrict__ X, ushort_t* __restrict__ Y, int n)
{
    int base = (blockIdx.x * 256 + threadIdx.x) * 4;
    if (base >= n) return;
    float4 v = *(const float4*)(X + base);
    Y[base + 0] = f2bf(v.x);
    Y[base + 1] = f2bf(v.y);
    Y[base + 2] = f2bf(v.z);
    Y[base + 3] = f2bf(v.w);
}

// ------------- weight transpose+convert: W[K][N] f32 -> Wt[Npad][K] bf16 -------------
__global__ __launch_bounds__(256) void convT_kernel(
    const float* __restrict__ W, ushort_t* __restrict__ Wt, int K, int N)
{
    __shared__ float tile[32][33];
    const int k0 = blockIdx.y * 32, n0 = blockIdx.x * 32;
    const int tr = threadIdx.x >> 5, tc = threadIdx.x & 31;
    #pragma unroll
    for (int i = 0; i < 4; ++i) {
        int r = tr + i * 8;
        float v = 0.f;
        if (n0 + tc < N) v = W[(size_t)(k0 + r) * N + n0 + tc];
        tile[r][tc] = v;
    }
    __syncthreads();
    #pragma unroll
    for (int i = 0; i < 4; ++i) {
        int r = tr + i * 8;  // n-index within tile
        Wt[(size_t)(n0 + r) * K + k0 + tc] = f2bf(tile[tc][r]);
    }
}

// ------- fused: rmsnorm-q (blocks 0..2047) + rmsnorm-kv (2048..4095) + rope-k (4096..4351) -------
__global__ __launch_bounds__(256) void fused_norm_ropek(
    const ushort_t* __restrict__ cat16r, ushort_t* __restrict__ qa16,
    ushort_t* __restrict__ ckv16n, ushort_t* __restrict__ kpe16,
    const float* __restrict__ qlnw, const float* __restrict__ klnw)
{
    __shared__ float red[4];
    const int b = blockIdx.x;
    if (b < 4096) {
        const bool isQ = (b < 2048);
        const int row = isQ ? b : b - 2048;
        const int K = isQ ? Q_LORA : KV_LORA;
        const ushort_t* x = cat16r + (size_t)row * 2176 + (isQ ? 0 : Q_LORA);
        ushort_t* y = (isQ ? qa16 + (size_t)row * Q_LORA : ckv16n + (size_t)row * KV_LORA);
        const float* wv = isQ ? qlnw : klnw;
        float ss = 0.f;
        for (int i = threadIdx.x; i < K; i += 256) { float v = bf2f(x[i]); ss += v * v; }
        #pragma unroll
        for (int off = 32; off > 0; off >>= 1) ss += __shfl_down(ss, off);
        int lane = threadIdx.x & 63, wid = threadIdx.x >> 6;
        if (lane == 0) red[wid] = ss;
        __syncthreads();
        float tot = red[0] + red[1] + red[2] + red[3];
        float rs = rsqrtf(tot / (float)K + 1e-6f);
        for (int i = threadIdx.x; i < K; i += 256)
            y[i] = f2bf(bf2f(x[i]) * rs * wv[i]);
    } else {
        int idx = (b - 4096) * 256 + threadIdx.x;
        if (idx >= S_LEN * 32) return;
        int i = idx & 31;
        int s = idx >> 5;
        float inv = powf(10000.0f, -(2.0f * i) / 64.0f);
        float ang = (float)s * inv;
        float c = cosf(ang), sn = sinf(ang);
        const ushort_t* p = cat16r + (size_t)s * 2176 + Q_LORA + KV_LORA;
        ushort_t* q = kpe16 + (size_t)s * D_ROPE;
        float x1 = bf2f(p[i]), x2 = bf2f(p[i + 32]);
        q[i]      = f2bf(x1 * c - x2 * sn);
        q[i + 32] = f2bf(x2 * c + x1 * sn);
    }
}

// ---------------- bf16 RoPE (q path) ----------------
__global__ void rope_bf16_kernel(
    ushort_t* __restrict__ X, int rowStride, int dimOffset, int headStride, int nHeads)
{
    int idx = blockIdx.x * 256 + threadIdx.x;
    if (idx >= S_LEN * nHeads * 32) return;
    int i = idx & 31;
    int sh = idx >> 5;
    int hh = sh % nHeads;
    int s = sh / nHeads;
    float inv = powf(10000.0f, -(2.0f * i) / 64.0f);
    float ang = (float)s * inv;
    float c = cosf(ang), sn = sinf(ang);
    ushort_t* p = X + (size_t)s * rowStride + hh * headStride + dimOffset;
    float x1 = bf2f(p[i]), x2 = bf2f(p[i + 32]);
    p[i]      = f2bf(x1 * c - x2 * sn);
    p[i + 32] = f2bf(x2 * c + x1 * sn);
}

// ---------------- V transpose: kv16[s][h*256+128+dv] -> v16t[h][dv][s] ----------------
__global__ __launch_bounds__(256) void conv_vT_kernel(
    const ushort_t* __restrict__ kv, ushort_t* __restrict__ v16t)
{
    __shared__ ushort_t tile[32][33];
    const int h = blockIdx.z;
    const int s0 = blockIdx.x * 32, d0 = blockIdx.y * 32;
    const int tr = threadIdx.x >> 5, tc = threadIdx.x & 31;
    #pragma unroll
    for (int i = 0; i < 4; ++i) {
        int r = tr + i * 8;  // s
        tile[r][tc] = kv[(size_t)(s0 + r) * 4096 + h * 256 + D_NOPE + d0 + tc];
    }
    __syncthreads();
    #pragma unroll
    for (int i = 0; i < 4; ++i) {
        int r = tr + i * 8;  // dv
        v16t[(size_t)h * D_V * S_LEN + (size_t)(d0 + r) * S_LEN + s0 + tc] = tile[tc][r];
    }
}

// ------- MFMA GEMM, 64x128 (MxN) tile: C[M][N] = A[M][K] * Bt[N][K]^T -------
template <typename CT>
__global__ __launch_bounds__(256) void mfma_gemm_bt(
    const ushort_t* __restrict__ A, const ushort_t* __restrict__ Bt,
    CT* __restrict__ C, int N, int K)
{
    __shared__ ushort_t Al[64 * 32];    // 4 KB
    __shared__ ushort_t Bl[128 * 32];   // 8 KB
    const int m0 = blockIdx.y * 64, n0 = blockIdx.x * 128;
    const int tid = threadIdx.x;
    const int lane = tid & 63;
    const int w = tid >> 6;
    const int lm = lane & 15, quad = lane >> 4;
    const int wr = w >> 1, wc = w & 1;

    f32x4 acc[2][4];
    #pragma unroll
    for (int a = 0; a < 2; ++a)
        #pragma unroll
        for (int b = 0; b < 4; ++b) acc[a][b] = (f32x4){0.f, 0.f, 0.f, 0.f};

    const int rrow = tid >> 2;
    const int rcol = (tid & 3) * 8;

    for (int k0 = 0; k0 < K; k0 += 32) {
        __syncthreads();
        gload_lds16(A + (size_t)(m0 + rrow) * K + k0 + rcol, Al + tid * 8);
        #pragma unroll
        for (int i = 0; i < 2; ++i) {
            int row = i * 64 + rrow;
            gload_lds16(Bt + (size_t)(n0 + row) * K + k0 + rcol, Bl + (i * 256 + tid) * 8);
        }
        __syncthreads();

        short8 af[2], bf[4];
        #pragma unroll
        for (int t = 0; t < 2; ++t)
            af[t] = *(const short8*)(Al + (wr * 32 + t * 16 + lm) * 32 + quad * 8);
        #pragma unroll
        for (int t = 0; t < 4; ++t)
            bf[t] = *(const short8*)(Bl + (wc * 64 + t * 16 + lm) * 32 + quad * 8);
        #pragma unroll
        for (int mt = 0; mt < 2; ++mt)
            #pragma unroll
            for (int nt = 0; nt < 4; ++nt)
                acc[mt][nt] = __builtin_amdgcn_mfma_f32_16x16x32_bf16(
                    af[mt], bf[nt], acc[mt][nt], 0, 0, 0);
    }

    #pragma unroll
    for (int mt = 0; mt < 2; ++mt)
        #pragma unroll
        for (int nt = 0; nt < 4; ++nt)
            #pragma unroll
            for (int r = 0; r < 4; ++r) {
                int row = m0 + wr * 32 + mt * 16 + quad * 4 + r;
                int col = n0 + wc * 64 + nt * 16 + lm;
                storeC(&C[(size_t)row * N + col], acc[mt][nt][r]);
            }
}

// online-softmax update for one 16x64 score tile in C layout (DPP); P -> ps[16][72]
__device__ __forceinline__ void softmax_step(
    f32x4 s[4], int k0, int qw, int lm, int quad,
    float m_[4], float l_[4], f32x4 O[8], ushort_t* ps)
{
    const float scale = 0.07216878364870322f;  // 192^-0.5
    #pragma unroll
    for (int r = 0; r < 4; ++r) {
        int qrow = qw + quad * 4 + r;
        float a[4];
        #pragma unroll
        for (int st = 0; st < 4; ++st)
            a[st] = (k0 + st * 16 + lm <= qrow) ? s[st][r] * scale : -1e30f;
        float mx = dpp_max16(fmaxf(fmaxf(a[0], a[1]), fmaxf(a[2], a[3])));
        float mn = fmaxf(m_[r], mx);
        float p[4];
        #pragma unroll
        for (int st = 0; st < 4; ++st) p[st] = __expf(a[st] - mn);
        float alpha = __expf(m_[r] - mn);
        float psum = dpp_sum16((p[0] + p[1]) + (p[2] + p[3]));
        l_[r] = l_[r] * alpha + psum;
        m_[r] = mn;
        #pragma unroll
        for (int c = 0; c < 8; ++c) O[c][r] *= alpha;
        #pragma unroll
        for (int st = 0; st < 4; ++st)
            ps[(quad * 4 + r) * 72 + st * 16 + lm] = f2bf(p[st]);
    }
}

// -------- MFMA flash attention: K in LDS, V direct from global, DPP softmax --------
// Grid (NH, 64), heavy-first (q0 = 32*(63-by)). 128 threads = 2 waves; wave w owns
// rows [q0+16w, q0+16w+16). Per 64-key round: stage K-nope/K-rope only (12
// global_load_lds/wave -> smaller barrier drain; LDS 28.5 KB -> 5 blocks/CU by
// LDS, 4/CU by grid). V fragments load global->VGPR before QK^T so their
// latency hides under 24 MFMA + softmax; v16t reads are per-lane 16B
// contiguous, L2-resident (512 KB/head).
__global__ __launch_bounds__(128) void mla_attn_kernel(
    const ushort_t* __restrict__ qb, const ushort_t* __restrict__ kvb,
    const ushort_t* __restrict__ kpe, const ushort_t* __restrict__ v16t,
    ushort_t* __restrict__ aout16)
{
    __shared__ ushort_t Kn[4 * 64 * 32];   // 16 KB [f 0..3][key 0..63][32]
    __shared__ ushort_t Kr[2 * 64 * 32];   //  8 KB [f2 0..1][key][32]
    __shared__ ushort_t Ps[2][16][72];     // 4.5 KB per-wave P

    const int h = blockIdx.x;
    const int q0 = 32 * (63 - blockIdx.y);  // heavy-first
    const int w = threadIdx.x >> 6;         // 0..1
    const int lane = threadIdx.x & 63;
    const int lm = lane & 15, quad = lane >> 4;
    const int qw = q0 + 16 * w;
    ushort_t* myPs = &Ps[w][0][0];
    const ushort_t* vh = v16t + (size_t)h * D_V * S_LEN;

    short8 qf[6];
    #pragma unroll
    for (int f = 0; f < 6; ++f)
        qf[f] = *(const short8*)(qb + (size_t)(qw + lm) * 3072 + h * 192 + f * 32 + quad * 8);

    f32x4 O[8];
    #pragma unroll
    for (int c = 0; c < 8; ++c) O[c] = (f32x4){0.f, 0.f, 0.f, 0.f};
    float m_[4] = {-1e30f, -1e30f, -1e30f, -1e30f};
    float l_[4] = {0.f, 0.f, 0.f, 0.f};

    const int skey = lane >> 2;        // 0..15
    const int ssub = (lane & 3) * 8;   // 0/8/16/24

    const int kend = q0 + 32;
    for (int k0 = 0; k0 < kend; k0 += 64) {
        __syncthreads();
        {
            // K-nope: wave w covers f in {2w, 2w+1}, i = 0..3 (8 instr/wave)
            #pragma unroll
            for (int fi = 0; fi < 2; ++fi) {
                int f = 2 * w + fi;
                #pragma unroll
                for (int i = 0; i < 4; ++i)
                    gload_lds16(kvb + (size_t)(k0 + i * 16 + skey) * 4096 + h * 256 + f * 32 + ssub,
                                Kn + f * 2048 + i * 512 + lane * 8);
            }
            // K-rope: f2 = w, i = 0..3 (4 instr/wave)
            #pragma unroll
            for (int i = 0; i < 4; ++i)
                gload_lds16(kpe + (size_t)(k0 + i * 16 + skey) * 64 + w * 32 + ssub,
                            Kr + w * 2048 + i * 512 + lane * 8);
        }
        __syncthreads();

        if (k0 < qw + 16) {  // wave-uniform causal skip (wave 1 always active)
            // ---- V fragment prefetch (global -> VGPR), overlaps QK+softmax ----
            const ushort_t* vbase = vh + (size_t)lm * S_LEN + k0 + quad * 8;
            short8 vf0[8], vf1[8];
            #pragma unroll
            for (int c = 0; c < 8; ++c) {
                vf0[c] = *(const short8*)(vbase + (size_t)c * 16 * S_LEN);
                vf1[c] = *(const short8*)(vbase + (size_t)c * 16 * S_LEN + 32);
            }
            // ---- S = Q K^T (4 key-subtiles of 16) ----
            f32x4 s[4];
            #pragma unroll
            for (int st = 0; st < 4; ++st) s[st] = (f32x4){0.f, 0.f, 0.f, 0.f};
            #pragma unroll
            for (int f = 0; f < 4; ++f)
                #pragma unroll
                for (int st = 0; st < 4; ++st) {
                    short8 kf = *(const short8*)(Kn + f * 2048 + (st * 16 + lm) * 32 + quad * 8);
                    s[st] = __builtin_amdgcn_mfma_f32_16x16x32_bf16(qf[f], kf, s[st], 0, 0, 0);
                }
            #pragma unroll
            for (int f2 = 0; f2 < 2; ++f2)
                #pragma unroll
                for (int st = 0; st < 4; ++st) {
                    short8 kf = *(const short8*)(Kr + f2 * 2048 + (st * 16 + lm) * 32 + quad * 8);
                    s[st] = __builtin_amdgcn_mfma_f32_16x16x32_bf16(qf[4 + f2], kf, s[st], 0, 0, 0);
                }

            softmax_step(s, k0, qw, lm, quad, m_, l_, O, myPs);

            asm volatile("s_waitcnt lgkmcnt(0)" ::: "memory");
            short8 pf0 = *(const short8*)(myPs + lm * 72 + quad * 8);
            short8 pf1 = *(const short8*)(myPs + lm * 72 + 32 + quad * 8);
            #pragma unroll
            for (int c = 0; c < 8; ++c) {
                O[c] = __builtin_amdgcn_mfma_f32_16x16x32_bf16(pf0, vf0[c], O[c], 0, 0, 0);
                O[c] = __builtin_amdgcn_mfma_f32_16x16x32_bf16(pf1, vf1[c], O[c], 0, 0, 0);
            }
        }
    }
    // epilogue
    #pragma unroll
    for (int c = 0; c < 8; ++c)
        #pragma unroll
        for (int r = 0; r < 4; ++r) {
            int qrow = qw + quad * 4 + r;
            aout16[(size_t)qrow * 2048 + h * D_V + c * 16 + lm] = f2bf(O[c][r] / l_[r]);
        }
}

extern "C" void kernel_launch(void* const* d_in, const int* in_sizes, int n_in,
                              void* d_out, int out_size, void* d_ws, size_t ws_size,
                              hipStream_t stream)
{
    (void)in_sizes; (void)n_in; (void)out_size; (void)ws_size;
    const float* hs   = (const float*)d_in[0];
    const float* Wqa  = (const float*)d_in[1];
    const float* qlnw = (const float*)d_in[2];
    const float* Wqb  = (const float*)d_in[3];
    const float* Wkva = (const float*)d_in[4];
    const float* klnw = (const float*)d_in[5];
    const float* Wkvb = (const float*)d_in[6];
    const float* Wo   = (const float*)d_in[7];
    float* out = (float*)d_out;

    ushort_t* p = (ushort_t*)d_ws;
    ushort_t* hs16   = p; p += (size_t)S_LEN * H_DIM;
    ushort_t* WcatT  = p; p += (size_t)2176 * H_DIM;     // [Wqa^T 1536 ; Wkva^T 640] x 2048
    ushort_t* WqbT   = p; p += (size_t)3072 * Q_LORA;
    ushort_t* WkvbT  = p; p += (size_t)4096 * KV_LORA;
    ushort_t* WoT    = p; p += (size_t)H_DIM * H_DIM;
    ushort_t* cat16r = p; p += (size_t)S_LEN * 2176;     // [qa_raw | ckv_raw | kpe_raw | pad]
    ushort_t* qa16   = p; p += (size_t)S_LEN * Q_LORA;
    ushort_t* qbuf16 = p; p += (size_t)S_LEN * 3072;
    ushort_t* ckv16n = p; p += (size_t)S_LEN * KV_LORA;
    ushort_t* kpe16  = p; p += (size_t)S_LEN * D_ROPE;
    ushort_t* kv16   = p; p += (size_t)S_LEN * 4096;
    ushort_t* v16t   = p; p += (size_t)NH * D_V * S_LEN;
    ushort_t* aout16 = p; p += (size_t)S_LEN * 2048;

    // 0. conversions
    conv_f32_bf16<<<(S_LEN * H_DIM / 4 + 255) / 256, 256, 0, stream>>>(hs, hs16, S_LEN * H_DIM);
    convT_kernel<<<dim3(Q_LORA / 32, H_DIM / 32), 256, 0, stream>>>(Wqa, WcatT, H_DIM, Q_LORA);
    convT_kernel<<<dim3(640 / 32, H_DIM / 32), 256, 0, stream>>>(
        Wkva, WcatT + (size_t)Q_LORA * H_DIM, H_DIM, 576);
    convT_kernel<<<dim3(3072 / 32, Q_LORA / 32), 256, 0, stream>>>(Wqb, WqbT, Q_LORA, 3072);
    convT_kernel<<<dim3(4096 / 32, KV_LORA / 32), 256, 0, stream>>>(Wkvb, WkvbT, KV_LORA, 4096);
    convT_kernel<<<dim3(H_DIM / 32, H_DIM / 32), 256, 0, stream>>>(Wo, WoT, H_DIM, H_DIM);

    // 1. cat16r = hs16 @ WcatT^T  [2048 x 2176, K=2048]  (fused Wqa + Wkva)
    mfma_gemm_bt<ushort_t><<<dim3(2176 / 128, S_LEN / 64), 256, 0, stream>>>(
        hs16, WcatT, cat16r, 2176, H_DIM);
    // 2. fused rmsnorm-q / rmsnorm-kv / rope-k
    fused_norm_ropek<<<4096 + 256, 256, 0, stream>>>(cat16r, qa16, ckv16n, kpe16, qlnw, klnw);
    // 3. qbuf16 = qa16 @ WqbT^T  [2048 x 3072, K=1536]
    mfma_gemm_bt<ushort_t><<<dim3(3072 / 128, S_LEN / 64), 256, 0, stream>>>(
        qa16, WqbT, qbuf16, 3072, Q_LORA);
    // 4. rope q (in place on qbuf16)
    rope_bf16_kernel<<<(S_LEN * NH * 32 + 255) / 256, 256, 0, stream>>>(
        qbuf16, 3072, D_NOPE, D_QK, NH);
    // 5. kv16 = ckv16n @ WkvbT^T [2048 x 4096, K=512]
    mfma_gemm_bt<ushort_t><<<dim3(4096 / 128, S_LEN / 64), 256, 0, stream>>>(
        ckv16n, WkvbT, kv16, 4096, KV_LORA);
    // 6. V transpose
    conv_vT_kernel<<<dim3(S_LEN / 32, D_V / 32, NH), 256, 0, stream>>>(kv16, v16t);
    // 7. attention (K in LDS, V direct from global)
    mla_attn_kernel<<<dim3(NH, 64), 128, 0, stream>>>(qbuf16, kv16, kpe16, v16t, aout16);
    // 8. out = aout16 @ WoT^T [2048 x 2048, K=2048], fp32 store
    mfma_gemm_bt<float><<<dim3(H_DIM / 128, S_LEN / 64), 256, 0, stream>>>(
        aout16, WoT, out, H_DIM, H_DIM);
}

// Round 12
// 353.184 us; speedup vs baseline: 1.1177x; 1.1177x over previous
//
#include <hip/hip_runtime.h>
#include <hip/hip_bf16.h>
#include <math.h>

#define S_LEN 2048
#define H_DIM 2048
#define NH 16
#define Q_LORA 1536
#define KV_LORA 512
#define D_NOPE 128
#define D_ROPE 64
#define D_V 128
#define D_QK 192

typedef unsigned short ushort_t;
typedef __attribute__((ext_vector_type(8))) short short8;
typedef __attribute__((ext_vector_type(4))) float f32x4;

__device__ __forceinline__ ushort_t f2bf(float f) {
    unsigned int u = __float_as_uint(f);
    u = (u + 0x7FFFu + ((u >> 16) & 1u)) >> 16;
    return (ushort_t)u;
}
__device__ __forceinline__ float bf2f(ushort_t u) {
    return __uint_as_float(((unsigned int)u) << 16);
}

__device__ __forceinline__ void storeC(float* p, float v) { *p = v; }
__device__ __forceinline__ void storeC(ushort_t* p, float v) { *p = f2bf(v); }

__device__ __forceinline__ void gload_lds16(const ushort_t* g, ushort_t* l) {
    __builtin_amdgcn_global_load_lds(
        (const __attribute__((address_space(1))) unsigned int*)(const void*)g,
        (__attribute__((address_space(3))) unsigned int*)(void*)l, 16, 0, 0);
}

// 16-lane DPP-row reductions (pure VALU)
__device__ __forceinline__ float dpp_max16(float x) {
    x = fmaxf(x, __int_as_float(__builtin_amdgcn_update_dpp(0, __float_as_int(x), 0xB1, 0xF, 0xF, true)));
    x = fmaxf(x, __int_as_float(__builtin_amdgcn_update_dpp(0, __float_as_int(x), 0x4E, 0xF, 0xF, true)));
    x = fmaxf(x, __int_as_float(__builtin_amdgcn_update_dpp(0, __float_as_int(x), 0x124, 0xF, 0xF, true)));
    x = fmaxf(x, __int_as_float(__builtin_amdgcn_update_dpp(0, __float_as_int(x), 0x128, 0xF, 0xF, true)));
    return x;
}
__device__ __forceinline__ float dpp_sum16(float x) {
    x += __int_as_float(__builtin_amdgcn_update_dpp(0, __float_as_int(x), 0xB1, 0xF, 0xF, true));
    x += __int_as_float(__builtin_amdgcn_update_dpp(0, __float_as_int(x), 0x4E, 0xF, 0xF, true));
    x += __int_as_float(__builtin_amdgcn_update_dpp(0, __float_as_int(x), 0x124, 0xF, 0xF, true));
    x += __int_as_float(__builtin_amdgcn_update_dpp(0, __float_as_int(x), 0x128, 0xF, 0xF, true));
    return x;
}

// ---------------- fp32 -> bf16 elementwise (n % 4 == 0) ----------------
__global__ __launch_bounds__(256) void conv_f32_bf16(
    const float* __restrict__ X, ushort_t* __restrict__ Y, int n)
{
    int base = (blockIdx.x * 256 + threadIdx.x) * 4;
    if (base >= n) return;
    float4 v = *(const float4*)(X + base);
    Y[base + 0] = f2bf(v.x);
    Y[base + 1] = f2bf(v.y);
    Y[base + 2] = f2bf(v.z);
    Y[base + 3] = f2bf(v.w);
}

// ------------- weight transpose+convert: W[K][N] f32 -> Wt[Npad][K] bf16 -------------
__global__ __launch_bounds__(256) void convT_kernel(
    const float* __restrict__ W, ushort_t* __restrict__ Wt, int K, int N)
{
    __shared__ float tile[32][33];
    const int k0 = blockIdx.y * 32, n0 = blockIdx.x * 32;
    const int tr = threadIdx.x >> 5, tc = threadIdx.x & 31;
    #pragma unroll
    for (int i = 0; i < 4; ++i) {
        int r = tr + i * 8;
        float v = 0.f;
        if (n0 + tc < N) v = W[(size_t)(k0 + r) * N + n0 + tc];
        tile[r][tc] = v;
    }
    __syncthreads();
    #pragma unroll
    for (int i = 0; i < 4; ++i) {
        int r = tr + i * 8;  // n-index within tile
        Wt[(size_t)(n0 + r) * K + k0 + tc] = f2bf(tile[tc][r]);
    }
}

// ------- fused: rmsnorm-q (blocks 0..2047) + rmsnorm-kv (2048..4095) + rope-k (4096..4351) -------
__global__ __launch_bounds__(256) void fused_norm_ropek(
    const ushort_t* __restrict__ cat16r, ushort_t* __restrict__ qa16,
    ushort_t* __restrict__ ckv16n, ushort_t* __restrict__ kpe16,
    const float* __restrict__ qlnw, const float* __restrict__ klnw)
{
    __shared__ float red[4];
    const int b = blockIdx.x;
    if (b < 4096) {
        const bool isQ = (b < 2048);
        const int row = isQ ? b : b - 2048;
        const int K = isQ ? Q_LORA : KV_LORA;
        const ushort_t* x = cat16r + (size_t)row * 2176 + (isQ ? 0 : Q_LORA);
        ushort_t* y = (isQ ? qa16 + (size_t)row * Q_LORA : ckv16n + (size_t)row * KV_LORA);
        const float* wv = isQ ? qlnw : klnw;
        float ss = 0.f;
        for (int i = threadIdx.x; i < K; i += 256) { float v = bf2f(x[i]); ss += v * v; }
        #pragma unroll
        for (int off = 32; off > 0; off >>= 1) ss += __shfl_down(ss, off);
        int lane = threadIdx.x & 63, wid = threadIdx.x >> 6;
        if (lane == 0) red[wid] = ss;
        __syncthreads();
        float tot = red[0] + red[1] + red[2] + red[3];
        float rs = rsqrtf(tot / (float)K + 1e-6f);
        for (int i = threadIdx.x; i < K; i += 256)
            y[i] = f2bf(bf2f(x[i]) * rs * wv[i]);
    } else {
        int idx = (b - 4096) * 256 + threadIdx.x;
        if (idx >= S_LEN * 32) return;
        int i = idx & 31;
        int s = idx >> 5;
        float inv = powf(10000.0f, -(2.0f * i) / 64.0f);
        float ang = (float)s * inv;
        float c = cosf(ang), sn = sinf(ang);
        const ushort_t* p = cat16r + (size_t)s * 2176 + Q_LORA + KV_LORA;
        ushort_t* q = kpe16 + (size_t)s * D_ROPE;
        float x1 = bf2f(p[i]), x2 = bf2f(p[i + 32]);
        q[i]      = f2bf(x1 * c - x2 * sn);
        q[i + 32] = f2bf(x2 * c + x1 * sn);
    }
}

// ---------------- bf16 RoPE (q path) ----------------
__global__ void rope_bf16_kernel(
    ushort_t* __restrict__ X, int rowStride, int dimOffset, int headStride, int nHeads)
{
    int idx = blockIdx.x * 256 + threadIdx.x;
    if (idx >= S_LEN * nHeads * 32) return;
    int i = idx & 31;
    int sh = idx >> 5;
    int hh = sh % nHeads;
    int s = sh / nHeads;
    float inv = powf(10000.0f, -(2.0f * i) / 64.0f);
    float ang = (float)s * inv;
    float c = cosf(ang), sn = sinf(ang);
    ushort_t* p = X + (size_t)s * rowStride + hh * headStride + dimOffset;
    float x1 = bf2f(p[i]), x2 = bf2f(p[i + 32]);
    p[i]      = f2bf(x1 * c - x2 * sn);
    p[i + 32] = f2bf(x2 * c + x1 * sn);
}

// ---------------- V transpose: kv16[s][h*256+128+dv] -> v16t[h][dv][s] ----------------
__global__ __launch_bounds__(256) void conv_vT_kernel(
    const ushort_t* __restrict__ kv, ushort_t* __restrict__ v16t)
{
    __shared__ ushort_t tile[32][33];
    const int h = blockIdx.z;
    const int s0 = blockIdx.x * 32, d0 = blockIdx.y * 32;
    const int tr = threadIdx.x >> 5, tc = threadIdx.x & 31;
    #pragma unroll
    for (int i = 0; i < 4; ++i) {
        int r = tr + i * 8;  // s
        tile[r][tc] = kv[(size_t)(s0 + r) * 4096 + h * 256 + D_NOPE + d0 + tc];
    }
    __syncthreads();
    #pragma unroll
    for (int i = 0; i < 4; ++i) {
        int r = tr + i * 8;  // dv
        v16t[(size_t)h * D_V * S_LEN + (size_t)(d0 + r) * S_LEN + s0 + tc] = tile[tc][r];
    }
}

// ---- MFMA GEMM body, 64x128 (MxN) tile, BK=64 (two 32-chunks per barrier) ----
// LDS 24 KB; per round: 6 gload/thread, 16 MFMA/wave. Halves barrier rounds vs BK=32.
template <typename CT>
__device__ __forceinline__ void gemm_body_bk64(
    const ushort_t* __restrict__ A, const ushort_t* __restrict__ Bt,
    CT* __restrict__ C, int N, int K, int m0, int n0,
    ushort_t* Al, ushort_t* Bl)  // Al: 2*64*32, Bl: 2*128*32
{
    const int tid = threadIdx.x;
    const int lane = tid & 63;
    const int w = tid >> 6;
    const int lm = lane & 15, quad = lane >> 4;
    const int wr = w >> 1, wc = w & 1;

    f32x4 acc[2][4];
    #pragma unroll
    for (int a = 0; a < 2; ++a)
        #pragma unroll
        for (int b = 0; b < 4; ++b) acc[a][b] = (f32x4){0.f, 0.f, 0.f, 0.f};

    const int rrow = tid >> 2;            // 0..63
    const int rcol = (tid & 3) * 8;       // 0/8/16/24

    for (int k0 = 0; k0 < K; k0 += 64) {
        __syncthreads();
        #pragma unroll
        for (int c = 0; c < 2; ++c) {
            gload_lds16(A + (size_t)(m0 + rrow) * K + k0 + c * 32 + rcol,
                        Al + c * 2048 + tid * 8);
            #pragma unroll
            for (int i = 0; i < 2; ++i)
                gload_lds16(Bt + (size_t)(n0 + i * 64 + rrow) * K + k0 + c * 32 + rcol,
                            Bl + c * 4096 + (i * 256 + tid) * 8);
        }
        __syncthreads();

        #pragma unroll
        for (int c = 0; c < 2; ++c) {
            short8 af[2], bf[4];
            #pragma unroll
            for (int t = 0; t < 2; ++t)
                af[t] = *(const short8*)(Al + c * 2048 + (wr * 32 + t * 16 + lm) * 32 + quad * 8);
            #pragma unroll
            for (int t = 0; t < 4; ++t)
                bf[t] = *(const short8*)(Bl + c * 4096 + (wc * 64 + t * 16 + lm) * 32 + quad * 8);
            #pragma unroll
            for (int mt = 0; mt < 2; ++mt)
                #pragma unroll
                for (int nt = 0; nt < 4; ++nt)
                    acc[mt][nt] = __builtin_amdgcn_mfma_f32_16x16x32_bf16(
                        af[mt], bf[nt], acc[mt][nt], 0, 0, 0);
        }
    }

    #pragma unroll
    for (int mt = 0; mt < 2; ++mt)
        #pragma unroll
        for (int nt = 0; nt < 4; ++nt)
            #pragma unroll
            for (int r = 0; r < 4; ++r) {
                int row = m0 + wr * 32 + mt * 16 + quad * 4 + r;
                int col = n0 + wc * 64 + nt * 16 + lm;
                storeC(&C[(size_t)row * N + col], acc[mt][nt][r]);
            }
}

template <typename CT>
__global__ __launch_bounds__(256) void mfma_gemm_bt(
    const ushort_t* __restrict__ A, const ushort_t* __restrict__ Bt,
    CT* __restrict__ C, int N, int K)
{
    __shared__ ushort_t Al[2 * 64 * 32];
    __shared__ ushort_t Bl[2 * 128 * 32];
    gemm_body_bk64<CT>(A, Bt, C, N, K, blockIdx.y * 64, blockIdx.x * 128, Al, Bl);
}

// grouped: blocks [0, nb1) -> GEMM1 (N1 x K1), rest -> GEMM2 (N2 x K2); both M=2048
__global__ __launch_bounds__(256) void mfma_gemm_dual(
    const ushort_t* __restrict__ A1, const ushort_t* __restrict__ Bt1,
    ushort_t* __restrict__ C1, int N1, int K1, int nb1,
    const ushort_t* __restrict__ A2, const ushort_t* __restrict__ Bt2,
    ushort_t* __restrict__ C2, int N2, int K2)
{
    __shared__ ushort_t Al[2 * 64 * 32];
    __shared__ ushort_t Bl[2 * 128 * 32];
    int g = blockIdx.x;
    if (g < nb1) {
        int nbx = N1 / 128;
        gemm_body_bk64<ushort_t>(A1, Bt1, C1, N1, K1, (g / nbx) * 64, (g % nbx) * 128, Al, Bl);
    } else {
        g -= nb1;
        int nbx = N2 / 128;
        gemm_body_bk64<ushort_t>(A2, Bt2, C2, N2, K2, (g / nbx) * 64, (g % nbx) * 128, Al, Bl);
    }
}

// online-softmax update for one 16x64 score tile in C layout (DPP); P -> ps[16][72]
__device__ __forceinline__ void softmax_step(
    f32x4 s[4], int k0, int qw, int lm, int quad,
    float m_[4], float l_[4], f32x4 O[8], ushort_t* ps)
{
    const float scale = 0.07216878364870322f;  // 192^-0.5
    #pragma unroll
    for (int r = 0; r < 4; ++r) {
        int qrow = qw + quad * 4 + r;
        float a[4];
        #pragma unroll
        for (int st = 0; st < 4; ++st)
            a[st] = (k0 + st * 16 + lm <= qrow) ? s[st][r] * scale : -1e30f;
        float mx = dpp_max16(fmaxf(fmaxf(a[0], a[1]), fmaxf(a[2], a[3])));
        float mn = fmaxf(m_[r], mx);
        float p[4];
        #pragma unroll
        for (int st = 0; st < 4; ++st) p[st] = __expf(a[st] - mn);
        float alpha = __expf(m_[r] - mn);
        float psum = dpp_sum16((p[0] + p[1]) + (p[2] + p[3]));
        l_[r] = l_[r] * alpha + psum;
        m_[r] = mn;
        #pragma unroll
        for (int c = 0; c < 8; ++c) O[c][r] *= alpha;
        #pragma unroll
        for (int st = 0; st < 4; ++st)
            ps[(quad * 4 + r) * 72 + st * 16 + lm] = f2bf(p[st]);
    }
}

// ---------------- MFMA flash attention (round-10 config: best measured) ----------------
// Grid (NH, 64), heavy-first. 128 threads = 2 waves; 64-key rounds; K-nope/K-rope/V^T
// all LDS-staged (44.5 KB -> 3 blocks/CU); DPP softmax.
__global__ __launch_bounds__(128) void mla_attn_kernel(
    const ushort_t* __restrict__ qb, const ushort_t* __restrict__ kvb,
    const ushort_t* __restrict__ kpe, const ushort_t* __restrict__ v16t,
    ushort_t* __restrict__ aout16)
{
    __shared__ ushort_t Kn[4 * 64 * 32];   // 16 KB
    __shared__ ushort_t Kr[2 * 64 * 32];   //  8 KB
    __shared__ ushort_t Vt[2 * 128 * 32];  // 16 KB
    __shared__ ushort_t Ps[2][16][72];     // 4.5 KB

    const int h = blockIdx.x;
    const int q0 = 32 * (63 - blockIdx.y);  // heavy-first
    const int w = threadIdx.x >> 6;         // 0..1
    const int lane = threadIdx.x & 63;
    const int lm = lane & 15, quad = lane >> 4;
    const int qw = q0 + 16 * w;
    ushort_t* myPs = &Ps[w][0][0];

    short8 qf[6];
    #pragma unroll
    for (int f = 0; f < 6; ++f)
        qf[f] = *(const short8*)(qb + (size_t)(qw + lm) * 3072 + h * 192 + f * 32 + quad * 8);

    f32x4 O[8];
    #pragma unroll
    for (int c = 0; c < 8; ++c) O[c] = (f32x4){0.f, 0.f, 0.f, 0.f};
    float m_[4] = {-1e30f, -1e30f, -1e30f, -1e30f};
    float l_[4] = {0.f, 0.f, 0.f, 0.f};

    const int skey = lane >> 2;        // 0..15
    const int ssub = (lane & 3) * 8;   // 0/8/16/24

    const int kend = q0 + 32;
    for (int k0 = 0; k0 < kend; k0 += 64) {
        __syncthreads();
        {
            #pragma unroll
            for (int fi = 0; fi < 2; ++fi) {
                int f = 2 * w + fi;
                #pragma unroll
                for (int i = 0; i < 4; ++i)
                    gload_lds16(kvb + (size_t)(k0 + i * 16 + skey) * 4096 + h * 256 + f * 32 + ssub,
                                Kn + f * 2048 + i * 512 + lane * 8);
            }
            #pragma unroll
            for (int i = 0; i < 4; ++i)
                gload_lds16(kpe + (size_t)(k0 + i * 16 + skey) * 64 + w * 32 + ssub,
                            Kr + w * 2048 + i * 512 + lane * 8);
            #pragma unroll
            for (int j = 0; j < 8; ++j)
                gload_lds16(v16t + ((size_t)h * 128 + j * 16 + skey) * S_LEN + k0 + w * 32 + ssub,
                            Vt + w * 4096 + j * 512 + lane * 8);
        }
        __syncthreads();

        if (k0 < qw + 16) {  // wave-uniform causal skip (wave 1 always active)
            f32x4 s[4];
            #pragma unroll
            for (int st = 0; st < 4; ++st) s[st] = (f32x4){0.f, 0.f, 0.f, 0.f};
            #pragma unroll
            for (int f = 0; f < 4; ++f)
                #pragma unroll
                for (int st = 0; st < 4; ++st) {
                    short8 kf = *(const short8*)(Kn + f * 2048 + (st * 16 + lm) * 32 + quad * 8);
                    s[st] = __builtin_amdgcn_mfma_f32_16x16x32_bf16(qf[f], kf, s[st], 0, 0, 0);
                }
            #pragma unroll
            for (int f2 = 0; f2 < 2; ++f2)
                #pragma unroll
                for (int st = 0; st < 4; ++st) {
                    short8 kf = *(const short8*)(Kr + f2 * 2048 + (st * 16 + lm) * 32 + quad * 8);
                    s[st] = __builtin_amdgcn_mfma_f32_16x16x32_bf16(qf[4 + f2], kf, s[st], 0, 0, 0);
                }

            softmax_step(s, k0, qw, lm, quad, m_, l_, O, myPs);

            asm volatile("s_waitcnt lgkmcnt(0)" ::: "memory");
            short8 pf0 = *(const short8*)(myPs + lm * 72 + quad * 8);
            short8 pf1 = *(const short8*)(myPs + lm * 72 + 32 + quad * 8);
            #pragma unroll
            for (int c = 0; c < 8; ++c) {
                short8 vf0 = *(const short8*)(Vt + (c * 16 + lm) * 32 + quad * 8);
                short8 vf1 = *(const short8*)(Vt + 4096 + (c * 16 + lm) * 32 + quad * 8);
                O[c] = __builtin_amdgcn_mfma_f32_16x16x32_bf16(pf0, vf0, O[c], 0, 0, 0);
                O[c] = __builtin_amdgcn_mfma_f32_16x16x32_bf16(pf1, vf1, O[c], 0, 0, 0);
            }
        }
    }
    // epilogue
    #pragma unroll
    for (int c = 0; c < 8; ++c)
        #pragma unroll
        for (int r = 0; r < 4; ++r) {
            int qrow = qw + quad * 4 + r;
            aout16[(size_t)qrow * 2048 + h * D_V + c * 16 + lm] = f2bf(O[c][r] / l_[r]);
        }
}

extern "C" void kernel_launch(void* const* d_in, const int* in_sizes, int n_in,
                              void* d_out, int out_size, void* d_ws, size_t ws_size,
                              hipStream_t stream)
{
    (void)in_sizes; (void)n_in; (void)out_size; (void)ws_size;
    const float* hs   = (const float*)d_in[0];
    const float* Wqa  = (const float*)d_in[1];
    const float* qlnw = (const float*)d_in[2];
    const float* Wqb  = (const float*)d_in[3];
    const float* Wkva = (const float*)d_in[4];
    const float* klnw = (const float*)d_in[5];
    const float* Wkvb = (const float*)d_in[6];
    const float* Wo   = (const float*)d_in[7];
    float* out = (float*)d_out;

    ushort_t* p = (ushort_t*)d_ws;
    ushort_t* hs16   = p; p += (size_t)S_LEN * H_DIM;
    ushort_t* WcatT  = p; p += (size_t)2176 * H_DIM;     // [Wqa^T 1536 ; Wkva^T 640] x 2048
    ushort_t* WqbT   = p; p += (size_t)3072 * Q_LORA;
    ushort_t* WkvbT  = p; p += (size_t)4096 * KV_LORA;
    ushort_t* WoT    = p; p += (size_t)H_DIM * H_DIM;
    ushort_t* cat16r = p; p += (size_t)S_LEN * 2176;     // [qa_raw | ckv_raw | kpe_raw | pad]
    ushort_t* qa16   = p; p += (size_t)S_LEN * Q_LORA;
    ushort_t* qbuf16 = p; p += (size_t)S_LEN * 3072;
    ushort_t* ckv16n = p; p += (size_t)S_LEN * KV_LORA;
    ushort_t* kpe16  = p; p += (size_t)S_LEN * D_ROPE;
    ushort_t* kv16   = p; p += (size_t)S_LEN * 4096;
    ushort_t* v16t   = p; p += (size_t)NH * D_V * S_LEN;
    ushort_t* aout16 = p; p += (size_t)S_LEN * 2048;

    // 0. conversions
    conv_f32_bf16<<<(S_LEN * H_DIM / 4 + 255) / 256, 256, 0, stream>>>(hs, hs16, S_LEN * H_DIM);
    convT_kernel<<<dim3(Q_LORA / 32, H_DIM / 32), 256, 0, stream>>>(Wqa, WcatT, H_DIM, Q_LORA);
    convT_kernel<<<dim3(640 / 32, H_DIM / 32), 256, 0, stream>>>(
        Wkva, WcatT + (size_t)Q_LORA * H_DIM, H_DIM, 576);
    convT_kernel<<<dim3(3072 / 32, Q_LORA / 32), 256, 0, stream>>>(Wqb, WqbT, Q_LORA, 3072);
    convT_kernel<<<dim3(4096 / 32, KV_LORA / 32), 256, 0, stream>>>(Wkvb, WkvbT, KV_LORA, 4096);
    convT_kernel<<<dim3(H_DIM / 32, H_DIM / 32), 256, 0, stream>>>(Wo, WoT, H_DIM, H_DIM);

    // 1. cat16r = hs16 @ WcatT^T  [2048 x 2176, K=2048]  (fused Wqa + Wkva)
    mfma_gemm_bt<ushort_t><<<dim3(2176 / 128, S_LEN / 64), 256, 0, stream>>>(
        hs16, WcatT, cat16r, 2176, H_DIM);
    // 2. fused rmsnorm-q / rmsnorm-kv / rope-k
    fused_norm_ropek<<<4096 + 256, 256, 0, stream>>>(cat16r, qa16, ckv16n, kpe16, qlnw, klnw);
    // 3. grouped GEMM: qbuf16 = qa16 @ WqbT^T  [2048x3072, K=1536]  (768 blocks)
    //                + kv16   = ckv16n @ WkvbT^T [2048x4096, K=512] (1024 blocks)
    mfma_gemm_dual<<<768 + 1024, 256, 0, stream>>>(
        qa16, WqbT, qbuf16, 3072, Q_LORA, 768,
        ckv16n, WkvbT, kv16, 4096, KV_LORA);
    // 4. rope q (in place on qbuf16)
    rope_bf16_kernel<<<(S_LEN * NH * 32 + 255) / 256, 256, 0, stream>>>(
        qbuf16, 3072, D_NOPE, D_QK, NH);
    // 5. V transpose
    conv_vT_kernel<<<dim3(S_LEN / 32, D_V / 32, NH), 256, 0, stream>>>(kv16, v16t);
    // 6. attention (round-10 config)
    mla_attn_kernel<<<dim3(NH, 64), 128, 0, stream>>>(qbuf16, kv16, kpe16, v16t, aout16);
    // 7. out = aout16 @ WoT^T [2048 x 2048, K=2048], fp32 store
    mfma_gemm_bt<float><<<dim3(H_DIM / 128, S_LEN / 64), 256, 0, stream>>>(
        aout16, WoT, out, H_DIM, H_DIM);
}

// Round 13
// 350.318 us; speedup vs baseline: 1.1268x; 1.0082x over previous
//
#include <hip/hip_runtime.h>
#include <hip/hip_bf16.h>
#include <math.h>

#define S_LEN 2048
#define H_DIM 2048
#define NH 16
#define Q_LORA 1536
#define KV_LORA 512
#define D_NOPE 128
#define D_ROPE 64
#define D_V 128
#define D_QK 192

typedef unsigned short ushort_t;
typedef __attribute__((ext_vector_type(8))) short short8;
typedef __attribute__((ext_vector_type(4))) float f32x4;

__device__ __forceinline__ ushort_t f2bf(float f) {
    unsigned int u = __float_as_uint(f);
    u = (u + 0x7FFFu + ((u >> 16) & 1u)) >> 16;
    return (ushort_t)u;
}
__device__ __forceinline__ float bf2f(ushort_t u) {
    return __uint_as_float(((unsigned int)u) << 16);
}

__device__ __forceinline__ void storeC(float* p, float v) { *p = v; }
__device__ __forceinline__ void storeC(ushort_t* p, float v) { *p = f2bf(v); }

__device__ __forceinline__ void gload_lds16(const ushort_t* g, ushort_t* l) {
    __builtin_amdgcn_global_load_lds(
        (const __attribute__((address_space(1))) unsigned int*)(const void*)g,
        (__attribute__((address_space(3))) unsigned int*)(void*)l, 16, 0, 0);
}

// 16-lane DPP-row reductions (pure VALU)
__device__ __forceinline__ float dpp_max16(float x) {
    x = fmaxf(x, __int_as_float(__builtin_amdgcn_update_dpp(0, __float_as_int(x), 0xB1, 0xF, 0xF, true)));
    x = fmaxf(x, __int_as_float(__builtin_amdgcn_update_dpp(0, __float_as_int(x), 0x4E, 0xF, 0xF, true)));
    x = fmaxf(x, __int_as_float(__builtin_amdgcn_update_dpp(0, __float_as_int(x), 0x124, 0xF, 0xF, true)));
    x = fmaxf(x, __int_as_float(__builtin_amdgcn_update_dpp(0, __float_as_int(x), 0x128, 0xF, 0xF, true)));
    return x;
}
__device__ __forceinline__ float dpp_sum16(float x) {
    x += __int_as_float(__builtin_amdgcn_update_dpp(0, __float_as_int(x), 0xB1, 0xF, 0xF, true));
    x += __int_as_float(__builtin_amdgcn_update_dpp(0, __float_as_int(x), 0x4E, 0xF, 0xF, true));
    x += __int_as_float(__builtin_amdgcn_update_dpp(0, __float_as_int(x), 0x124, 0xF, 0xF, true));
    x += __int_as_float(__builtin_amdgcn_update_dpp(0, __float_as_int(x), 0x128, 0xF, 0xF, true));
    return x;
}

// -------- unified conversion: hs f32->bf16 + 5 weight transposes, one launch --------
__device__ __forceinline__ void convT_body(
    const float* __restrict__ W, ushort_t* __restrict__ Wt,
    int K, int N, int n0, int k0, float (*tile)[33])
{
    const int tr = threadIdx.x >> 5, tc = threadIdx.x & 31;
    #pragma unroll
    for (int i = 0; i < 4; ++i) {
        int r = tr + i * 8;
        float v = 0.f;
        if (n0 + tc < N) v = W[(size_t)(k0 + r) * N + n0 + tc];
        tile[r][tc] = v;
    }
    __syncthreads();
    #pragma unroll
    for (int i = 0; i < 4; ++i) {
        int r = tr + i * 8;
        Wt[(size_t)(n0 + r) * K + k0 + tc] = f2bf(tile[tc][r]);
    }
}

__global__ __launch_bounds__(256) void unified_conv(
    const float* __restrict__ hs, ushort_t* __restrict__ hs16,
    const float* __restrict__ Wqa, const float* __restrict__ Wkva,
    const float* __restrict__ Wqb, const float* __restrict__ Wkvb,
    const float* __restrict__ Wo,
    ushort_t* __restrict__ WcatT, ushort_t* __restrict__ WqbT,
    ushort_t* __restrict__ WkvbT, ushort_t* __restrict__ WoT)
{
    __shared__ float tile[32][33];
    int b = blockIdx.x;
    if (b < 4096) {   // hs elementwise
        int base = (b * 256 + threadIdx.x) * 4;
        float4 v = *(const float4*)(hs + base);
        hs16[base + 0] = f2bf(v.x);
        hs16[base + 1] = f2bf(v.y);
        hs16[base + 2] = f2bf(v.z);
        hs16[base + 3] = f2bf(v.w);
        return;
    }
    b -= 4096;
    const float* W; ushort_t* Wt; int K, N, nbx;
    if (b < 3072)        {            W = Wqa;  Wt = WcatT;                              K = 2048; N = 1536; nbx = 48;  }
    else if (b < 4352)   { b -= 3072; W = Wkva; Wt = WcatT + (size_t)Q_LORA * H_DIM;     K = 2048; N = 576;  nbx = 20;  }
    else if (b < 8960)   { b -= 4352; W = Wqb;  Wt = WqbT;                               K = 1536; N = 3072; nbx = 96;  }
    else if (b < 11008)  { b -= 8960; W = Wkvb; Wt = WkvbT;                              K = 512;  N = 4096; nbx = 128; }
    else                 { b -= 11008; W = Wo;  Wt = WoT;                                K = 2048; N = 2048; nbx = 64;  }
    convT_body(W, Wt, K, N, (b % nbx) * 32, (b / nbx) * 32, tile);
}

// ------- fused: rmsnorm-q (blocks 0..2047) + rmsnorm-kv (2048..4095) + rope-k (4096..) -------
__global__ __launch_bounds__(256) void fused_norm_ropek(
    const ushort_t* __restrict__ cat16r, ushort_t* __restrict__ qa16,
    ushort_t* __restrict__ ckv16n, ushort_t* __restrict__ kpe16,
    const float* __restrict__ qlnw, const float* __restrict__ klnw)
{
    __shared__ float red[4];
    const int b = blockIdx.x;
    if (b < 4096) {
        const bool isQ = (b < 2048);
        const int row = isQ ? b : b - 2048;
        const int K = isQ ? Q_LORA : KV_LORA;
        const ushort_t* x = cat16r + (size_t)row * 2176 + (isQ ? 0 : Q_LORA);
        ushort_t* y = (isQ ? qa16 + (size_t)row * Q_LORA : ckv16n + (size_t)row * KV_LORA);
        const float* wv = isQ ? qlnw : klnw;
        float ss = 0.f;
        for (int i = threadIdx.x; i < K; i += 256) { float v = bf2f(x[i]); ss += v * v; }
        #pragma unroll
        for (int off = 32; off > 0; off >>= 1) ss += __shfl_down(ss, off);
        int lane = threadIdx.x & 63, wid = threadIdx.x >> 6;
        if (lane == 0) red[wid] = ss;
        __syncthreads();
        float tot = red[0] + red[1] + red[2] + red[3];
        float rs = rsqrtf(tot / (float)K + 1e-6f);
        for (int i = threadIdx.x; i < K; i += 256)
            y[i] = f2bf(bf2f(x[i]) * rs * wv[i]);
    } else {
        int idx = (b - 4096) * 256 + threadIdx.x;
        if (idx >= S_LEN * 32) return;
        int i = idx & 31;
        int s = idx >> 5;
        float inv = powf(10000.0f, -(2.0f * i) / 64.0f);
        float ang = (float)s * inv;
        float c = cosf(ang), sn = sinf(ang);
        const ushort_t* p = cat16r + (size_t)s * 2176 + Q_LORA + KV_LORA;
        ushort_t* q = kpe16 + (size_t)s * D_ROPE;
        float x1 = bf2f(p[i]), x2 = bf2f(p[i + 32]);
        q[i]      = f2bf(x1 * c - x2 * sn);
        q[i + 32] = f2bf(x2 * c + x1 * sn);
    }
}

// ---------------- V transpose: kv16[s][h*256+128+dv] -> v16t[h][dv][s] ----------------
__global__ __launch_bounds__(256) void conv_vT_kernel(
    const ushort_t* __restrict__ kv, ushort_t* __restrict__ v16t)
{
    __shared__ ushort_t tile[32][33];
    const int h = blockIdx.z;
    const int s0 = blockIdx.x * 32, d0 = blockIdx.y * 32;
    const int tr = threadIdx.x >> 5, tc = threadIdx.x & 31;
    #pragma unroll
    for (int i = 0; i < 4; ++i) {
        int r = tr + i * 8;  // s
        tile[r][tc] = kv[(size_t)(s0 + r) * 4096 + h * 256 + D_NOPE + d0 + tc];
    }
    __syncthreads();
    #pragma unroll
    for (int i = 0; i < 4; ++i) {
        int r = tr + i * 8;  // dv
        v16t[(size_t)h * D_V * S_LEN + (size_t)(d0 + r) * S_LEN + s0 + tc] = tile[tc][r];
    }
}

// ---- MFMA GEMM body, 64x128 (MxN) tile, BK=64 (two 32-chunks per barrier) ----
template <typename CT>
__device__ __forceinline__ void gemm_body_bk64(
    const ushort_t* __restrict__ A, const ushort_t* __restrict__ Bt,
    CT* __restrict__ C, int N, int K, int m0, int n0,
    ushort_t* Al, ushort_t* Bl)  // Al: 2*64*32, Bl: 2*128*32
{
    const int tid = threadIdx.x;
    const int lane = tid & 63;
    const int w = tid >> 6;
    const int lm = lane & 15, quad = lane >> 4;
    const int wr = w >> 1, wc = w & 1;

    f32x4 acc[2][4];
    #pragma unroll
    for (int a = 0; a < 2; ++a)
        #pragma unroll
        for (int b = 0; b < 4; ++b) acc[a][b] = (f32x4){0.f, 0.f, 0.f, 0.f};

    const int rrow = tid >> 2;
    const int rcol = (tid & 3) * 8;

    for (int k0 = 0; k0 < K; k0 += 64) {
        __syncthreads();
        #pragma unroll
        for (int c = 0; c < 2; ++c) {
            gload_lds16(A + (size_t)(m0 + rrow) * K + k0 + c * 32 + rcol,
                        Al + c * 2048 + tid * 8);
            #pragma unroll
            for (int i = 0; i < 2; ++i)
                gload_lds16(Bt + (size_t)(n0 + i * 64 + rrow) * K + k0 + c * 32 + rcol,
                            Bl + c * 4096 + (i * 256 + tid) * 8);
        }
        __syncthreads();

        #pragma unroll
        for (int c = 0; c < 2; ++c) {
            short8 af[2], bf[4];
            #pragma unroll
            for (int t = 0; t < 2; ++t)
                af[t] = *(const short8*)(Al + c * 2048 + (wr * 32 + t * 16 + lm) * 32 + quad * 8);
            #pragma unroll
            for (int t = 0; t < 4; ++t)
                bf[t] = *(const short8*)(Bl + c * 4096 + (wc * 64 + t * 16 + lm) * 32 + quad * 8);
            #pragma unroll
            for (int mt = 0; mt < 2; ++mt)
                #pragma unroll
                for (int nt = 0; nt < 4; ++nt)
                    acc[mt][nt] = __builtin_amdgcn_mfma_f32_16x16x32_bf16(
                        af[mt], bf[nt], acc[mt][nt], 0, 0, 0);
        }
    }

    #pragma unroll
    for (int mt = 0; mt < 2; ++mt)
        #pragma unroll
        for (int nt = 0; nt < 4; ++nt)
            #pragma unroll
            for (int r = 0; r < 4; ++r) {
                int row = m0 + wr * 32 + mt * 16 + quad * 4 + r;
                int col = n0 + wc * 64 + nt * 16 + lm;
                storeC(&C[(size_t)row * N + col], acc[mt][nt][r]);
            }
}

template <typename CT>
__global__ __launch_bounds__(256) void mfma_gemm_bt(
    const ushort_t* __restrict__ A, const ushort_t* __restrict__ Bt,
    CT* __restrict__ C, int N, int K)
{
    __shared__ ushort_t Al[2 * 64 * 32];
    __shared__ ushort_t Bl[2 * 128 * 32];
    gemm_body_bk64<CT>(A, Bt, C, N, K, blockIdx.y * 64, blockIdx.x * 128, Al, Bl);
}

__global__ __launch_bounds__(256) void mfma_gemm_dual(
    const ushort_t* __restrict__ A1, const ushort_t* __restrict__ Bt1,
    ushort_t* __restrict__ C1, int N1, int K1, int nb1,
    const ushort_t* __restrict__ A2, const ushort_t* __restrict__ Bt2,
    ushort_t* __restrict__ C2, int N2, int K2)
{
    __shared__ ushort_t Al[2 * 64 * 32];
    __shared__ ushort_t Bl[2 * 128 * 32];
    int g = blockIdx.x;
    if (g < nb1) {
        int nbx = N1 / 128;
        gemm_body_bk64<ushort_t>(A1, Bt1, C1, N1, K1, (g / nbx) * 64, (g % nbx) * 128, Al, Bl);
    } else {
        g -= nb1;
        int nbx = N2 / 128;
        gemm_body_bk64<ushort_t>(A2, Bt2, C2, N2, K2, (g / nbx) * 64, (g % nbx) * 128, Al, Bl);
    }
}

// online-softmax update for one 16x64 score tile in C layout (DPP); P -> ps[16][72]
__device__ __forceinline__ void softmax_step(
    f32x4 s[4], int k0, int qw, int lm, int quad,
    float m_[4], float l_[4], f32x4 O[8], ushort_t* ps)
{
    const float scale = 0.07216878364870322f;  // 192^-0.5
    #pragma unroll
    for (int r = 0; r < 4; ++r) {
        int qrow = qw + quad * 4 + r;
        float a[4];
        #pragma unroll
        for (int st = 0; st < 4; ++st)
            a[st] = (k0 + st * 16 + lm <= qrow) ? s[st][r] * scale : -1e30f;
        float mx = dpp_max16(fmaxf(fmaxf(a[0], a[1]), fmaxf(a[2], a[3])));
        float mn = fmaxf(m_[r], mx);
        float p[4];
        #pragma unroll
        for (int st = 0; st < 4; ++st) p[st] = __expf(a[st] - mn);
        float alpha = __expf(m_[r] - mn);
        float psum = dpp_sum16((p[0] + p[1]) + (p[2] + p[3]));
        l_[r] = l_[r] * alpha + psum;
        m_[r] = mn;
        #pragma unroll
        for (int c = 0; c < 8; ++c) O[c][r] *= alpha;
        #pragma unroll
        for (int st = 0; st < 4; ++st)
            ps[(quad * 4 + r) * 72 + st * 16 + lm] = f2bf(p[st]);
    }
}

// ------ MFMA flash attention: Kn/Vt in LDS (36.5 KB -> 4 blocks/CU, all 1024
// resident), kpe prefetched to VGPRs under the staging drain, fused RoPE-q,
// DPP softmax, 64-key rounds, 2-wave blocks, heavy-first. ------
__global__ __launch_bounds__(128) void mla_attn_kernel(
    const ushort_t* __restrict__ qb, const ushort_t* __restrict__ kvb,
    const ushort_t* __restrict__ kpe, const ushort_t* __restrict__ v16t,
    ushort_t* __restrict__ aout16)
{
    __shared__ ushort_t Kn[4 * 64 * 32];   // 16 KB
    __shared__ ushort_t Vt[2 * 128 * 32];  // 16 KB
    __shared__ ushort_t Ps[2][16][72];     // 4.5 KB

    const int h = blockIdx.x;
    const int q0 = 32 * (63 - blockIdx.y);  // heavy-first
    const int w = threadIdx.x >> 6;         // 0..1
    const int lane = threadIdx.x & 63;
    const int lm = lane & 15, quad = lane >> 4;
    const int qw = q0 + 16 * w;
    ushort_t* myPs = &Ps[w][0][0];

    // Q fragments (un-roped source) + fused RoPE on chunks 4/5
    short8 qf[6];
    #pragma unroll
    for (int f = 0; f < 6; ++f)
        qf[f] = *(const short8*)(qb + (size_t)(qw + lm) * 3072 + h * 192 + f * 32 + quad * 8);
    {
        float srow = (float)(qw + lm);
        #pragma unroll
        for (int j = 0; j < 8; ++j) {
            int i = quad * 8 + j;
            float inv = powf(10000.0f, -(2.0f * i) / 64.0f);
            float ang = srow * inv;
            float c = cosf(ang), sn = sinf(ang);
            float x1 = bf2f((ushort_t)qf[4][j]);
            float x2 = bf2f((ushort_t)qf[5][j]);
            qf[4][j] = (short)f2bf(x1 * c - x2 * sn);
            qf[5][j] = (short)f2bf(x2 * c + x1 * sn);
        }
    }

    f32x4 O[8];
    #pragma unroll
    for (int c = 0; c < 8; ++c) O[c] = (f32x4){0.f, 0.f, 0.f, 0.f};
    float m_[4] = {-1e30f, -1e30f, -1e30f, -1e30f};
    float l_[4] = {0.f, 0.f, 0.f, 0.f};

    const int skey = lane >> 2;        // 0..15
    const int ssub = (lane & 3) * 8;   // 0/8/16/24

    const int kend = q0 + 32;
    for (int k0 = 0; k0 < kend; k0 += 64) {
        __syncthreads();
        // kpe -> VGPR prefetch; its latency is covered by the staging vmcnt(0) drain
        short8 krf[2][4];
        #pragma unroll
        for (int st = 0; st < 4; ++st)
            #pragma unroll
            for (int f2 = 0; f2 < 2; ++f2)
                krf[f2][st] = *(const short8*)(
                    kpe + (size_t)(k0 + st * 16 + lm) * 64 + f2 * 32 + quad * 8);
        {
            // K-nope: wave w covers f in {2w, 2w+1}, i = 0..3 (8 instr/wave)
            #pragma unroll
            for (int fi = 0; fi < 2; ++fi) {
                int f = 2 * w + fi;
                #pragma unroll
                for (int i = 0; i < 4; ++i)
                    gload_lds16(kvb + (size_t)(k0 + i * 16 + skey) * 4096 + h * 256 + f * 32 + ssub,
                                Kn + f * 2048 + i * 512 + lane * 8);
            }
            // V^T: half = w, j = 0..7 (8 instr/wave)
            #pragma unroll
            for (int j = 0; j < 8; ++j)
                gload_lds16(v16t + ((size_t)h * 128 + j * 16 + skey) * S_LEN + k0 + w * 32 + ssub,
                            Vt + w * 4096 + j * 512 + lane * 8);
        }
        __syncthreads();

        if (k0 < qw + 16) {  // wave-uniform causal skip (wave 1 always active)
            f32x4 s[4];
            #pragma unroll
            for (int st = 0; st < 4; ++st) s[st] = (f32x4){0.f, 0.f, 0.f, 0.f};
            #pragma unroll
            for (int f = 0; f < 4; ++f)
                #pragma unroll
                for (int st = 0; st < 4; ++st) {
                    short8 kf = *(const short8*)(Kn + f * 2048 + (st * 16 + lm) * 32 + quad * 8);
                    s[st] = __builtin_amdgcn_mfma_f32_16x16x32_bf16(qf[f], kf, s[st], 0, 0, 0);
                }
            #pragma unroll
            for (int f2 = 0; f2 < 2; ++f2)
                #pragma unroll
                for (int st = 0; st < 4; ++st)
                    s[st] = __builtin_amdgcn_mfma_f32_16x16x32_bf16(qf[4 + f2], krf[f2][st], s[st], 0, 0, 0);

            softmax_step(s, k0, qw, lm, quad, m_, l_, O, myPs);

            asm volatile("s_waitcnt lgkmcnt(0)" ::: "memory");
            short8 pf0 = *(const short8*)(myPs + lm * 72 + quad * 8);
            short8 pf1 = *(const short8*)(myPs + lm * 72 + 32 + quad * 8);
            #pragma unroll
            for (int c = 0; c < 8; ++c) {
                short8 vf0 = *(const short8*)(Vt + (c * 16 + lm) * 32 + quad * 8);
                short8 vf1 = *(const short8*)(Vt + 4096 + (c * 16 + lm) * 32 + quad * 8);
                O[c] = __builtin_amdgcn_mfma_f32_16x16x32_bf16(pf0, vf0, O[c], 0, 0, 0);
                O[c] = __builtin_amdgcn_mfma_f32_16x16x32_bf16(pf1, vf1, O[c], 0, 0, 0);
            }
        }
    }
    // epilogue
    #pragma unroll
    for (int c = 0; c < 8; ++c)
        #pragma unroll
        for (int r = 0; r < 4; ++r) {
            int qrow = qw + quad * 4 + r;
            aout16[(size_t)qrow * 2048 + h * D_V + c * 16 + lm] = f2bf(O[c][r] / l_[r]);
        }
}

extern "C" void kernel_launch(void* const* d_in, const int* in_sizes, int n_in,
                              void* d_out, int out_size, void* d_ws, size_t ws_size,
                              hipStream_t stream)
{
    (void)in_sizes; (void)n_in; (void)out_size; (void)ws_size;
    const float* hs   = (const float*)d_in[0];
    const float* Wqa  = (const float*)d_in[1];
    const float* qlnw = (const float*)d_in[2];
    const float* Wqb  = (const float*)d_in[3];
    const float* Wkva = (const float*)d_in[4];
    const float* klnw = (const float*)d_in[5];
    const float* Wkvb = (const float*)d_in[6];
    const float* Wo   = (const float*)d_in[7];
    float* out = (float*)d_out;

    ushort_t* p = (ushort_t*)d_ws;
    ushort_t* hs16   = p; p += (size_t)S_LEN * H_DIM;
    ushort_t* WcatT  = p; p += (size_t)2176 * H_DIM;     // [Wqa^T 1536 ; Wkva^T 640] x 2048
    ushort_t* WqbT   = p; p += (size_t)3072 * Q_LORA;
    ushort_t* WkvbT  = p; p += (size_t)4096 * KV_LORA;
    ushort_t* WoT    = p; p += (size_t)H_DIM * H_DIM;
    ushort_t* cat16r = p; p += (size_t)S_LEN * 2176;     // [qa_raw | ckv_raw | kpe_raw | pad]
    ushort_t* qa16   = p; p += (size_t)S_LEN * Q_LORA;
    ushort_t* qbuf16 = p; p += (size_t)S_LEN * 3072;
    ushort_t* ckv16n = p; p += (size_t)S_LEN * KV_LORA;
    ushort_t* kpe16  = p; p += (size_t)S_LEN * D_ROPE;
    ushort_t* kv16   = p; p += (size_t)S_LEN * 4096;
    ushort_t* v16t   = p; p += (size_t)NH * D_V * S_LEN;
    ushort_t* aout16 = p; p += (size_t)S_LEN * 2048;

    // 1. all conversions in one launch (hs + 5 weight transposes)
    unified_conv<<<19200, 256, 0, stream>>>(
        hs, hs16, Wqa, Wkva, Wqb, Wkvb, Wo, WcatT, WqbT, WkvbT, WoT);
    // 2. cat16r = hs16 @ WcatT^T  [2048 x 2176, K=2048]  (fused Wqa + Wkva)
    mfma_gemm_bt<ushort_t><<<dim3(2176 / 128, S_LEN / 64), 256, 0, stream>>>(
        hs16, WcatT, cat16r, 2176, H_DIM);
    // 3. fused rmsnorm-q / rmsnorm-kv / rope-k
    fused_norm_ropek<<<4096 + 256, 256, 0, stream>>>(cat16r, qa16, ckv16n, kpe16, qlnw, klnw);
    // 4. grouped GEMM: qbuf16 = qa16 @ WqbT^T [2048x3072,K=1536] + kv16 = ckv16n @ WkvbT^T [2048x4096,K=512]
    mfma_gemm_dual<<<768 + 1024, 256, 0, stream>>>(
        qa16, WqbT, qbuf16, 3072, Q_LORA, 768,
        ckv16n, WkvbT, kv16, 4096, KV_LORA);
    // 5. V transpose
    conv_vT_kernel<<<dim3(S_LEN / 32, D_V / 32, NH), 256, 0, stream>>>(kv16, v16t);
    // 6. attention (36.5 KB LDS, kpe VGPR prefetch, fused RoPE-q)
    mla_attn_kernel<<<dim3(NH, 64), 128, 0, stream>>>(qbuf16, kv16, kpe16, v16t, aout16);
    // 7. out = aout16 @ WoT^T [2048 x 2048, K=2048], fp32 store
    mfma_gemm_bt<float><<<dim3(H_DIM / 128, S_LEN / 64), 256, 0, stream>>>(
        aout16, WoT, out, H_DIM, H_DIM);
}

// Round 14
// 334.863 us; speedup vs baseline: 1.1788x; 1.0462x over previous
//
#include <hip/hip_runtime.h>
#include <hip/hip_bf16.h>
#include <math.h>

#define S_LEN 2048
#define H_DIM 2048
#define NH 16
#define Q_LORA 1536
#define KV_LORA 512
#define D_NOPE 128
#define D_ROPE 64
#define D_V 128
#define D_QK 192

typedef unsigned short ushort_t;
typedef __attribute__((ext_vector_type(8))) short short8;
typedef __attribute__((ext_vector_type(4))) float f32x4;

__device__ __forceinline__ ushort_t f2bf(float f) {
    unsigned int u = __float_as_uint(f);
    u = (u + 0x7FFFu + ((u >> 16) & 1u)) >> 16;
    return (ushort_t)u;
}
__device__ __forceinline__ float bf2f(ushort_t u) {
    return __uint_as_float(((unsigned int)u) << 16);
}

__device__ __forceinline__ void storeC(float* p, float v) { *p = v; }
__device__ __forceinline__ void storeC(ushort_t* p, float v) { *p = f2bf(v); }

__device__ __forceinline__ void gload_lds16(const ushort_t* g, ushort_t* l) {
    __builtin_amdgcn_global_load_lds(
        (const __attribute__((address_space(1))) unsigned int*)(const void*)g,
        (__attribute__((address_space(3))) unsigned int*)(void*)l, 16, 0, 0);
}

// 16-lane DPP-row reductions (pure VALU)
__device__ __forceinline__ float dpp_max16(float x) {
    x = fmaxf(x, __int_as_float(__builtin_amdgcn_update_dpp(0, __float_as_int(x), 0xB1, 0xF, 0xF, true)));
    x = fmaxf(x, __int_as_float(__builtin_amdgcn_update_dpp(0, __float_as_int(x), 0x4E, 0xF, 0xF, true)));
    x = fmaxf(x, __int_as_float(__builtin_amdgcn_update_dpp(0, __float_as_int(x), 0x124, 0xF, 0xF, true)));
    x = fmaxf(x, __int_as_float(__builtin_amdgcn_update_dpp(0, __float_as_int(x), 0x128, 0xF, 0xF, true)));
    return x;
}
__device__ __forceinline__ float dpp_sum16(float x) {
    x += __int_as_float(__builtin_amdgcn_update_dpp(0, __float_as_int(x), 0xB1, 0xF, 0xF, true));
    x += __int_as_float(__builtin_amdgcn_update_dpp(0, __float_as_int(x), 0x4E, 0xF, 0xF, true));
    x += __int_as_float(__builtin_amdgcn_update_dpp(0, __float_as_int(x), 0x124, 0xF, 0xF, true));
    x += __int_as_float(__builtin_amdgcn_update_dpp(0, __float_as_int(x), 0x128, 0xF, 0xF, true));
    return x;
}

// -------- unified conversion: hs f32->bf16 + 5 weight transposes, one launch --------
__device__ __forceinline__ void convT_body(
    const float* __restrict__ W, ushort_t* __restrict__ Wt,
    int K, int N, int n0, int k0, float (*tile)[33])
{
    const int tr = threadIdx.x >> 5, tc = threadIdx.x & 31;
    #pragma unroll
    for (int i = 0; i < 4; ++i) {
        int r = tr + i * 8;
        float v = 0.f;
        if (n0 + tc < N) v = W[(size_t)(k0 + r) * N + n0 + tc];
        tile[r][tc] = v;
    }
    __syncthreads();
    #pragma unroll
    for (int i = 0; i < 4; ++i) {
        int r = tr + i * 8;
        Wt[(size_t)(n0 + r) * K + k0 + tc] = f2bf(tile[tc][r]);
    }
}

__global__ __launch_bounds__(256) void unified_conv(
    const float* __restrict__ hs, ushort_t* __restrict__ hs16,
    const float* __restrict__ Wqa, const float* __restrict__ Wkva,
    const float* __restrict__ Wqb, const float* __restrict__ Wkvb,
    const float* __restrict__ Wo,
    ushort_t* __restrict__ WcatT, ushort_t* __restrict__ WqbT,
    ushort_t* __restrict__ WkvbT, ushort_t* __restrict__ WoT)
{
    __shared__ float tile[32][33];
    int b = blockIdx.x;
    if (b < 4096) {   // hs elementwise
        int base = (b * 256 + threadIdx.x) * 4;
        float4 v = *(const float4*)(hs + base);
        hs16[base + 0] = f2bf(v.x);
        hs16[base + 1] = f2bf(v.y);
        hs16[base + 2] = f2bf(v.z);
        hs16[base + 3] = f2bf(v.w);
        return;
    }
    b -= 4096;
    const float* W; ushort_t* Wt; int K, N, nbx;
    if (b < 3072)        {            W = Wqa;  Wt = WcatT;                              K = 2048; N = 1536; nbx = 48;  }
    else if (b < 4352)   { b -= 3072; W = Wkva; Wt = WcatT + (size_t)Q_LORA * H_DIM;     K = 2048; N = 576;  nbx = 20;  }
    else if (b < 8960)   { b -= 4352; W = Wqb;  Wt = WqbT;                               K = 1536; N = 3072; nbx = 96;  }
    else if (b < 11008)  { b -= 8960; W = Wkvb; Wt = WkvbT;                              K = 512;  N = 4096; nbx = 128; }
    else                 { b -= 11008; W = Wo;  Wt = WoT;                                K = 2048; N = 2048; nbx = 64;  }
    convT_body(W, Wt, K, N, (b % nbx) * 32, (b / nbx) * 32, tile);
}

// ------- fused: rmsnorm-q (blocks 0..2047) + rmsnorm-kv (2048..4095) + rope-k (4096..) -------
__global__ __launch_bounds__(256) void fused_norm_ropek(
    const ushort_t* __restrict__ cat16r, ushort_t* __restrict__ qa16,
    ushort_t* __restrict__ ckv16n, ushort_t* __restrict__ kpe16,
    const float* __restrict__ qlnw, const float* __restrict__ klnw)
{
    __shared__ float red[4];
    const int b = blockIdx.x;
    if (b < 4096) {
        const bool isQ = (b < 2048);
        const int row = isQ ? b : b - 2048;
        const int K = isQ ? Q_LORA : KV_LORA;
        const ushort_t* x = cat16r + (size_t)row * 2176 + (isQ ? 0 : Q_LORA);
        ushort_t* y = (isQ ? qa16 + (size_t)row * Q_LORA : ckv16n + (size_t)row * KV_LORA);
        const float* wv = isQ ? qlnw : klnw;
        float ss = 0.f;
        for (int i = threadIdx.x; i < K; i += 256) { float v = bf2f(x[i]); ss += v * v; }
        #pragma unroll
        for (int off = 32; off > 0; off >>= 1) ss += __shfl_down(ss, off);
        int lane = threadIdx.x & 63, wid = threadIdx.x >> 6;
        if (lane == 0) red[wid] = ss;
        __syncthreads();
        float tot = red[0] + red[1] + red[2] + red[3];
        float rs = rsqrtf(tot / (float)K + 1e-6f);
        for (int i = threadIdx.x; i < K; i += 256)
            y[i] = f2bf(bf2f(x[i]) * rs * wv[i]);
    } else {
        int idx = (b - 4096) * 256 + threadIdx.x;
        if (idx >= S_LEN * 32) return;
        int i = idx & 31;
        int s = idx >> 5;
        float inv = powf(10000.0f, -(2.0f * i) / 64.0f);
        float ang = (float)s * inv;
        float c = cosf(ang), sn = sinf(ang);
        const ushort_t* p = cat16r + (size_t)s * 2176 + Q_LORA + KV_LORA;
        ushort_t* q = kpe16 + (size_t)s * D_ROPE;
        float x1 = bf2f(p[i]), x2 = bf2f(p[i + 32]);
        q[i]      = f2bf(x1 * c - x2 * sn);
        q[i + 32] = f2bf(x2 * c + x1 * sn);
    }
}

// ---------------- V transpose: kv16[s][h*256+128+dv] -> v16t[h][dv][s] ----------------
__global__ __launch_bounds__(256) void conv_vT_kernel(
    const ushort_t* __restrict__ kv, ushort_t* __restrict__ v16t)
{
    __shared__ ushort_t tile[32][33];
    const int h = blockIdx.z;
    const int s0 = blockIdx.x * 32, d0 = blockIdx.y * 32;
    const int tr = threadIdx.x >> 5, tc = threadIdx.x & 31;
    #pragma unroll
    for (int i = 0; i < 4; ++i) {
        int r = tr + i * 8;  // s
        tile[r][tc] = kv[(size_t)(s0 + r) * 4096 + h * 256 + D_NOPE + d0 + tc];
    }
    __syncthreads();
    #pragma unroll
    for (int i = 0; i < 4; ++i) {
        int r = tr + i * 8;  // dv
        v16t[(size_t)h * D_V * S_LEN + (size_t)(d0 + r) * S_LEN + s0 + tc] = tile[tc][r];
    }
}

// ---- MFMA GEMM body, 64x128 (MxN) tile, BK=64 (two 32-chunks per barrier) ----
template <typename CT>
__device__ __forceinline__ void gemm_body_bk64(
    const ushort_t* __restrict__ A, const ushort_t* __restrict__ Bt,
    CT* __restrict__ C, int N, int K, int m0, int n0,
    ushort_t* Al, ushort_t* Bl)  // Al: 2*64*32, Bl: 2*128*32
{
    const int tid = threadIdx.x;
    const int lane = tid & 63;
    const int w = tid >> 6;
    const int lm = lane & 15, quad = lane >> 4;
    const int wr = w >> 1, wc = w & 1;

    f32x4 acc[2][4];
    #pragma unroll
    for (int a = 0; a < 2; ++a)
        #pragma unroll
        for (int b = 0; b < 4; ++b) acc[a][b] = (f32x4){0.f, 0.f, 0.f, 0.f};

    const int rrow = tid >> 2;
    const int rcol = (tid & 3) * 8;

    for (int k0 = 0; k0 < K; k0 += 64) {
        __syncthreads();
        #pragma unroll
        for (int c = 0; c < 2; ++c) {
            gload_lds16(A + (size_t)(m0 + rrow) * K + k0 + c * 32 + rcol,
                        Al + c * 2048 + tid * 8);
            #pragma unroll
            for (int i = 0; i < 2; ++i)
                gload_lds16(Bt + (size_t)(n0 + i * 64 + rrow) * K + k0 + c * 32 + rcol,
                            Bl + c * 4096 + (i * 256 + tid) * 8);
        }
        __syncthreads();

        #pragma unroll
        for (int c = 0; c < 2; ++c) {
            short8 af[2], bf[4];
            #pragma unroll
            for (int t = 0; t < 2; ++t)
                af[t] = *(const short8*)(Al + c * 2048 + (wr * 32 + t * 16 + lm) * 32 + quad * 8);
            #pragma unroll
            for (int t = 0; t < 4; ++t)
                bf[t] = *(const short8*)(Bl + c * 4096 + (wc * 64 + t * 16 + lm) * 32 + quad * 8);
            #pragma unroll
            for (int mt = 0; mt < 2; ++mt)
                #pragma unroll
                for (int nt = 0; nt < 4; ++nt)
                    acc[mt][nt] = __builtin_amdgcn_mfma_f32_16x16x32_bf16(
                        af[mt], bf[nt], acc[mt][nt], 0, 0, 0);
        }
    }

    #pragma unroll
    for (int mt = 0; mt < 2; ++mt)
        #pragma unroll
        for (int nt = 0; nt < 4; ++nt)
            #pragma unroll
            for (int r = 0; r < 4; ++r) {
                int row = m0 + wr * 32 + mt * 16 + quad * 4 + r;
                int col = n0 + wc * 64 + nt * 16 + lm;
                storeC(&C[(size_t)row * N + col], acc[mt][nt][r]);
            }
}

template <typename CT>
__global__ __launch_bounds__(256) void mfma_gemm_bt(
    const ushort_t* __restrict__ A, const ushort_t* __restrict__ Bt,
    CT* __restrict__ C, int N, int K)
{
    __shared__ ushort_t Al[2 * 64 * 32];
    __shared__ ushort_t Bl[2 * 128 * 32];
    gemm_body_bk64<CT>(A, Bt, C, N, K, blockIdx.y * 64, blockIdx.x * 128, Al, Bl);
}

__global__ __launch_bounds__(256) void mfma_gemm_dual(
    const ushort_t* __restrict__ A1, const ushort_t* __restrict__ Bt1,
    ushort_t* __restrict__ C1, int N1, int K1, int nb1,
    const ushort_t* __restrict__ A2, const ushort_t* __restrict__ Bt2,
    ushort_t* __restrict__ C2, int N2, int K2)
{
    __shared__ ushort_t Al[2 * 64 * 32];
    __shared__ ushort_t Bl[2 * 128 * 32];
    int g = blockIdx.x;
    if (g < nb1) {
        int nbx = N1 / 128;
        gemm_body_bk64<ushort_t>(A1, Bt1, C1, N1, K1, (g / nbx) * 64, (g % nbx) * 128, Al, Bl);
    } else {
        g -= nb1;
        int nbx = N2 / 128;
        gemm_body_bk64<ushort_t>(A2, Bt2, C2, N2, K2, (g / nbx) * 64, (g % nbx) * 128, Al, Bl);
    }
}

// online-softmax update for one 16x64 score tile in C layout (DPP); P -> ps[16][72]
__device__ __forceinline__ void softmax_step(
    f32x4 s[4], int k0, int qw, int lm, int quad,
    float m_[4], float l_[4], f32x4 O[8], ushort_t* ps)
{
    const float scale = 0.07216878364870322f;  // 192^-0.5
    #pragma unroll
    for (int r = 0; r < 4; ++r) {
        int qrow = qw + quad * 4 + r;
        float a[4];
        #pragma unroll
        for (int st = 0; st < 4; ++st)
            a[st] = (k0 + st * 16 + lm <= qrow) ? s[st][r] * scale : -1e30f;
        float mx = dpp_max16(fmaxf(fmaxf(a[0], a[1]), fmaxf(a[2], a[3])));
        float mn = fmaxf(m_[r], mx);
        float p[4];
        #pragma unroll
        for (int st = 0; st < 4; ++st) p[st] = __expf(a[st] - mn);
        float alpha = __expf(m_[r] - mn);
        float psum = dpp_sum16((p[0] + p[1]) + (p[2] + p[3]));
        l_[r] = l_[r] * alpha + psum;
        m_[r] = mn;
        #pragma unroll
        for (int c = 0; c < 8; ++c) O[c][r] *= alpha;
        #pragma unroll
        for (int st = 0; st < 4; ++st)
            ps[(quad * 4 + r) * 72 + st * 16 + lm] = f2bf(p[st]);
    }
}

// ---- MFMA flash attention (round-12 staging config, best measured 77.6 µs)
// + fused RoPE-q (one-time, replaces the rope launch). Kn/Kr/Vt LDS-staged
// (44.5 KB), DPP softmax, 64-key rounds, 2-wave blocks, heavy-first. ----
__global__ __launch_bounds__(128) void mla_attn_kernel(
    const ushort_t* __restrict__ qb, const ushort_t* __restrict__ kvb,
    const ushort_t* __restrict__ kpe, const ushort_t* __restrict__ v16t,
    ushort_t* __restrict__ aout16)
{
    __shared__ ushort_t Kn[4 * 64 * 32];   // 16 KB
    __shared__ ushort_t Kr[2 * 64 * 32];   //  8 KB
    __shared__ ushort_t Vt[2 * 128 * 32];  // 16 KB
    __shared__ ushort_t Ps[2][16][72];     // 4.5 KB

    const int h = blockIdx.x;
    const int q0 = 32 * (63 - blockIdx.y);  // heavy-first
    const int w = threadIdx.x >> 6;         // 0..1
    const int lane = threadIdx.x & 63;
    const int lm = lane & 15, quad = lane >> 4;
    const int qw = q0 + 16 * w;
    ushort_t* myPs = &Ps[w][0][0];

    // Q fragments (un-roped source) + fused RoPE on chunks 4/5
    short8 qf[6];
    #pragma unroll
    for (int f = 0; f < 6; ++f)
        qf[f] = *(const short8*)(qb + (size_t)(qw + lm) * 3072 + h * 192 + f * 32 + quad * 8);
    {
        float srow = (float)(qw + lm);
        #pragma unroll
        for (int j = 0; j < 8; ++j) {
            int i = quad * 8 + j;
            float inv = powf(10000.0f, -(2.0f * i) / 64.0f);
            float ang = srow * inv;
            float c = cosf(ang), sn = sinf(ang);
            float x1 = bf2f((ushort_t)qf[4][j]);
            float x2 = bf2f((ushort_t)qf[5][j]);
            qf[4][j] = (short)f2bf(x1 * c - x2 * sn);
            qf[5][j] = (short)f2bf(x2 * c + x1 * sn);
        }
    }

    f32x4 O[8];
    #pragma unroll
    for (int c = 0; c < 8; ++c) O[c] = (f32x4){0.f, 0.f, 0.f, 0.f};
    float m_[4] = {-1e30f, -1e30f, -1e30f, -1e30f};
    float l_[4] = {0.f, 0.f, 0.f, 0.f};

    const int skey = lane >> 2;        // 0..15
    const int ssub = (lane & 3) * 8;   // 0/8/16/24

    const int kend = q0 + 32;
    for (int k0 = 0; k0 < kend; k0 += 64) {
        __syncthreads();
        {
            // K-nope: wave w covers f in {2w, 2w+1}, i = 0..3 (8 instr/wave)
            #pragma unroll
            for (int fi = 0; fi < 2; ++fi) {
                int f = 2 * w + fi;
                #pragma unroll
                for (int i = 0; i < 4; ++i)
                    gload_lds16(kvb + (size_t)(k0 + i * 16 + skey) * 4096 + h * 256 + f * 32 + ssub,
                                Kn + f * 2048 + i * 512 + lane * 8);
            }
            // K-rope: f2 = w, i = 0..3 (4 instr/wave)
            #pragma unroll
            for (int i = 0; i < 4; ++i)
                gload_lds16(kpe + (size_t)(k0 + i * 16 + skey) * 64 + w * 32 + ssub,
                            Kr + w * 2048 + i * 512 + lane * 8);
            // V^T: half = w, j = 0..7 (8 instr/wave)
            #pragma unroll
            for (int j = 0; j < 8; ++j)
                gload_lds16(v16t + ((size_t)h * 128 + j * 16 + skey) * S_LEN + k0 + w * 32 + ssub,
                            Vt + w * 4096 + j * 512 + lane * 8);
        }
        __syncthreads();

        if (k0 < qw + 16) {  // wave-uniform causal skip (wave 1 always active)
            f32x4 s[4];
            #pragma unroll
            for (int st = 0; st < 4; ++st) s[st] = (f32x4){0.f, 0.f, 0.f, 0.f};
            #pragma unroll
            for (int f = 0; f < 4; ++f)
                #pragma unroll
                for (int st = 0; st < 4; ++st) {
                    short8 kf = *(const short8*)(Kn + f * 2048 + (st * 16 + lm) * 32 + quad * 8);
                    s[st] = __builtin_amdgcn_mfma_f32_16x16x32_bf16(qf[f], kf, s[st], 0, 0, 0);
                }
            #pragma unroll
            for (int f2 = 0; f2 < 2; ++f2)
                #pragma unroll
                for (int st = 0; st < 4; ++st) {
                    short8 kf = *(const short8*)(Kr + f2 * 2048 + (st * 16 + lm) * 32 + quad * 8);
                    s[st] = __builtin_amdgcn_mfma_f32_16x16x32_bf16(qf[4 + f2], kf, s[st], 0, 0, 0);
                }

            softmax_step(s, k0, qw, lm, quad, m_, l_, O, myPs);

            asm volatile("s_waitcnt lgkmcnt(0)" ::: "memory");
            short8 pf0 = *(const short8*)(myPs + lm * 72 + quad * 8);
            short8 pf1 = *(const short8*)(myPs + lm * 72 + 32 + quad * 8);
            #pragma unroll
            for (int c = 0; c < 8; ++c) {
                short8 vf0 = *(const short8*)(Vt + (c * 16 + lm) * 32 + quad * 8);
                short8 vf1 = *(const short8*)(Vt + 4096 + (c * 16 + lm) * 32 + quad * 8);
                O[c] = __builtin_amdgcn_mfma_f32_16x16x32_bf16(pf0, vf0, O[c], 0, 0, 0);
                O[c] = __builtin_amdgcn_mfma_f32_16x16x32_bf16(pf1, vf1, O[c], 0, 0, 0);
            }
        }
    }
    // epilogue
    #pragma unroll
    for (int c = 0; c < 8; ++c)
        #pragma unroll
        for (int r = 0; r < 4; ++r) {
            int qrow = qw + quad * 4 + r;
            aout16[(size_t)qrow * 2048 + h * D_V + c * 16 + lm] = f2bf(O[c][r] / l_[r]);
        }
}

extern "C" void kernel_launch(void* const* d_in, const int* in_sizes, int n_in,
                              void* d_out, int out_size, void* d_ws, size_t ws_size,
                              hipStream_t stream)
{
    (void)in_sizes; (void)n_in; (void)out_size; (void)ws_size;
    const float* hs   = (const float*)d_in[0];
    const float* Wqa  = (const float*)d_in[1];
    const float* qlnw = (const float*)d_in[2];
    const float* Wqb  = (const float*)d_in[3];
    const float* Wkva = (const float*)d_in[4];
    const float* klnw = (const float*)d_in[5];
    const float* Wkvb = (const float*)d_in[6];
    const float* Wo   = (const float*)d_in[7];
    float* out = (float*)d_out;

    ushort_t* p = (ushort_t*)d_ws;
    ushort_t* hs16   = p; p += (size_t)S_LEN * H_DIM;
    ushort_t* WcatT  = p; p += (size_t)2176 * H_DIM;     // [Wqa^T 1536 ; Wkva^T 640] x 2048
    ushort_t* WqbT   = p; p += (size_t)3072 * Q_LORA;
    ushort_t* WkvbT  = p; p += (size_t)4096 * KV_LORA;
    ushort_t* WoT    = p; p += (size_t)H_DIM * H_DIM;
    ushort_t* cat16r = p; p += (size_t)S_LEN * 2176;     // [qa_raw | ckv_raw | kpe_raw | pad]
    ushort_t* qa16   = p; p += (size_t)S_LEN * Q_LORA;
    ushort_t* qbuf16 = p; p += (size_t)S_LEN * 3072;
    ushort_t* ckv16n = p; p += (size_t)S_LEN * KV_LORA;
    ushort_t* kpe16  = p; p += (size_t)S_LEN * D_ROPE;
    ushort_t* kv16   = p; p += (size_t)S_LEN * 4096;
    ushort_t* v16t   = p; p += (size_t)NH * D_V * S_LEN;
    ushort_t* aout16 = p; p += (size_t)S_LEN * 2048;

    // 1. all conversions in one launch (hs + 5 weight transposes)
    unified_conv<<<19200, 256, 0, stream>>>(
        hs, hs16, Wqa, Wkva, Wqb, Wkvb, Wo, WcatT, WqbT, WkvbT, WoT);
    // 2. cat16r = hs16 @ WcatT^T  [2048 x 2176, K=2048]  (fused Wqa + Wkva)
    mfma_gemm_bt<ushort_t><<<dim3(2176 / 128, S_LEN / 64), 256, 0, stream>>>(
        hs16, WcatT, cat16r, 2176, H_DIM);
    // 3. fused rmsnorm-q / rmsnorm-kv / rope-k
    fused_norm_ropek<<<4096 + 256, 256, 0, stream>>>(cat16r, qa16, ckv16n, kpe16, qlnw, klnw);
    // 4. grouped GEMM: qbuf16 = qa16 @ WqbT^T [2048x3072,K=1536] + kv16 = ckv16n @ WkvbT^T [2048x4096,K=512]
    mfma_gemm_dual<<<768 + 1024, 256, 0, stream>>>(
        qa16, WqbT, qbuf16, 3072, Q_LORA, 768,
        ckv16n, WkvbT, kv16, 4096, KV_LORA);
    // 5. V transpose
    conv_vT_kernel<<<dim3(S_LEN / 32, D_V / 32, NH), 256, 0, stream>>>(kv16, v16t);
    // 6. attention (round-12 staging + fused RoPE-q)
    mla_attn_kernel<<<dim3(NH, 64), 128, 0, stream>>>(qbuf16, kv16, kpe16, v16t, aout16);
    // 7. out = aout16 @ WoT^T [2048 x 2048, K=2048], fp32 store
    mfma_gemm_bt<float><<<dim3(H_DIM / 128, S_LEN / 64), 256, 0, stream>>>(
        aout16, WoT, out, H_DIM, H_DIM);
}